// Round 5
// baseline (245.518 us; speedup 1.0000x reference)
//
#include <hip/hip_runtime.h>
#include <math.h>

typedef __attribute__((ext_vector_type(8)))  short short8;   // 8 x bf16 (4 VGPR) MFMA operand
typedef __attribute__((ext_vector_type(16))) float float16;  // 32x32 MFMA accumulator

#define DEVI __device__ __forceinline__

DEVI short f2bf(float f) {                      // RNE float -> bf16 bits
    unsigned u = __float_as_uint(f);
    u = (u + 0x7fffu + ((u >> 16) & 1u)) >> 16;
    return (short)u;
}
DEVI unsigned pk2(float a, float b) {
    return (unsigned)(unsigned short)f2bf(a) | ((unsigned)(unsigned short)f2bf(b) << 16);
}
DEVI float16 mfma16(short8 a, short8 b, float16 c) {
    return __builtin_amdgcn_mfma_f32_32x32x16_bf16(a, b, c, 0, 0, 0);
}
// C/D row for reg r, half h: row = (r&3) + 8*(r>>2) + 4*h  [verified R1-R4]
DEVI int rowof(int r, int h) { return (r & 3) + 8 * (r >> 2) + 4 * h; }
DEVI short8 lds8(const short* p) { return *(const short8*)p; }
DEVI short8 gld8(const short* p) { return *(const short8*)p; }

// ---- ws layout (shorts): MFMA-native [ceil(K/16)][N][16] bf16 ----
#define W1T_OFF  0          // [23][512][16] (K=365 pad 368)
#define W2T_OFF  188416     // [32][256][16]
#define W3T_OFF  319488     // [16][128][16]
#define WC1T_OFF 352256     // [10][64][16]
#define WC2T_OFF 362496     // [4][32][16]

// ---------------- prologue: coalesced transpose via LDS tiles ----------------
__global__ void prep_v2(const float* __restrict__ W1, const float* __restrict__ W2,
                        const float* __restrict__ W3, const float* __restrict__ Wc1,
                        const float* __restrict__ Wc2, short* __restrict__ ws) {
    __shared__ short T[16 * 72];
    int b = blockIdx.x, t = threadIdx.x;
    const float* src; int K, N; size_t base; int kc, nb;
    if (b < 184)        {            src = W1;  K = 365; N = 512; base = W1T_OFF;  kc = b >> 3;  nb = b & 7; }
    else if (b < 312)   { int l = b - 184; src = W2;  K = 512; N = 256; base = W2T_OFF;  kc = l >> 2;  nb = l & 3; }
    else if (b < 344)   { int l = b - 312; src = W3;  K = 256; N = 128; base = W3T_OFF;  kc = l >> 1;  nb = l & 1; }
    else if (b < 354)   {            src = Wc1; K = 160; N = 64;  base = WC1T_OFF; kc = b - 344; nb = 0; }
    else                {            src = Wc2; K = 64;  N = 32;  base = WC2T_OFF; kc = b - 354; nb = 0; }
    int n = nb * 64 + (t & 63);
    int kr = t >> 6;
    #pragma unroll
    for (int i = 0; i < 4; ++i) {
        int krow = kr + 4 * i;
        int k = kc * 16 + krow;
        float v = (k < K && n < N) ? src[(size_t)k * N + n] : 0.f;
        T[krow * 72 + (t & 63)] = f2bf(v);
    }
    __syncthreads();
    int n2 = t >> 2, ksq = (t & 3) * 4;
    int ng = nb * 64 + n2;
    if (ng < N) {
        unsigned lo = (unsigned)(unsigned short)T[ksq * 72 + n2]
                    | ((unsigned)(unsigned short)T[(ksq + 1) * 72 + n2] << 16);
        unsigned hi = (unsigned)(unsigned short)T[(ksq + 2) * 72 + n2]
                    | ((unsigned)(unsigned short)T[(ksq + 3) * 72 + n2] << 16);
        uint2 d; d.x = lo; d.y = hi;
        *(uint2*)(ws + base + ((size_t)kc * N + ng) * 16 + ksq) = d;
    }
}

// ---------------- fused main: BM=64, 1024 blocks x 256 threads ----------------
// v5: 4 waves/block, 256-reg budget (2 waves/SIMD). Each wave owns 128 h1-cols
// -> 1 A-read feeds 4 MFMAs. G1 straight-line (no barriers), h1 parked in 64
// packed VGPRs; single-barrier-per-slab double-buffered G2/G3. 11 barriers.
__global__ __launch_bounds__(256, 2)
void fused_v5(const float* __restrict__ x,
              const float* __restrict__ b1f, const float* __restrict__ b2f,
              const float* __restrict__ b3f, const float* __restrict__ Wsf,
              const float* __restrict__ bsf, const float* __restrict__ bc1f,
              const float* __restrict__ bc2f, const float* __restrict__ Wc3f,
              const float* __restrict__ bc3f,
              const short* __restrict__ wsw, float* __restrict__ out)
{
    __shared__ __align__(16) char smem[53248];
    short* XT    = (short*)smem;               // [64][376] bf16 x-tile (48128 B)
    short* SB0   = (short*)smem;               // [64][136] slab A (aliases XT after G1)
    short* SB1   = (short*)(smem + 17408);     // [64][136] slab B
    float* C2f   = (float*)(smem + 36864);     // [64][33] f32 (8448 B)
    short* FEATL = (short*)(smem + 48128);     // [64][40] bf16 (5120 B)

    const short* W1t  = wsw + W1T_OFF;
    const short* W2t  = wsw + W2T_OFF;
    const short* W3t  = wsw + W3T_OFF;
    const short* Wc1t = wsw + WC1T_OFF;
    const short* Wc2t = wsw + WC2T_OFF;

    const int tid  = (int)threadIdx.x;
    const int lane = tid & 63;
    const int wv   = tid >> 6;       // 0..3
    const int m    = lane & 31;
    const int h    = lane >> 5;
    const int rowBase = (int)blockIdx.x * 64;

    // ---- bias prefetch (overlaps x-phase) ----
    float bb1[2][2], bb2[2];
    #pragma unroll
    for (int p = 0; p < 2; ++p)
    #pragma unroll
    for (int ct = 0; ct < 2; ++ct) bb1[p][ct] = b1f[256 * p + 64 * wv + 32 * ct + m];
    bb2[0] = b2f[64 * wv + m]; bb2[1] = b2f[64 * wv + 32 + m];
    float bb3  = b3f[32 * wv + m];
    float bbc1 = bc1f[32 * (wv & 1) + m];
    float bbc2 = bc2f[m];

    // ---- fill XT + fused row moments (4 threads/row, octet-interleaved) ----
    const int r0 = tid >> 2, q = tid & 2 ? (tid & 3) : (tid & 3);   // q = tid&3
    const int qq = tid & 3;
    const float* xrow = x + (size_t)(rowBase + r0) * 365;
    float s1 = 0.f, s2 = 0.f, s3 = 0.f, s4 = 0.f, mn = 1e30f, mx = -1e30f;
    #pragma unroll
    for (int i = 0; i < 12; ++i) {
        int o = qq + 4 * i;
        if (o <= 45) {
            float xf[8];
            #pragma unroll
            for (int jj = 0; jj < 8; ++jj) {
                int col = o * 8 + jj;
                xf[jj] = (col < 365) ? xrow[col] : 0.f;
            }
            #pragma unroll
            for (int jj = 0; jj < 8; ++jj) {
                int col = o * 8 + jj;
                if (col < 365) {
                    float v = xf[jj], v2 = v * v;
                    s1 += v; s2 += v2; s3 += v2 * v; s4 += v2 * v2;
                    mn = fminf(mn, v); mx = fmaxf(mx, v);
                }
            }
            int4 w4;
            w4.x = (int)pk2(xf[0], xf[1]); w4.y = (int)pk2(xf[2], xf[3]);
            w4.z = (int)pk2(xf[4], xf[5]); w4.w = (int)pk2(xf[6], xf[7]);
            *(int4*)(XT + r0 * 376 + o * 8) = w4;
        }
    }
    // reduce moments across the 4 lanes sharing a row
    #pragma unroll
    for (int off = 1; off <= 2; off <<= 1) {
        s1 += __shfl_xor(s1, off); s2 += __shfl_xor(s2, off);
        s3 += __shfl_xor(s3, off); s4 += __shfl_xor(s4, off);
        mn = fminf(mn, __shfl_xor(mn, off)); mx = fmaxf(mx, __shfl_xor(mx, off));
    }
    {   // stats -> feat (8 cols/thread), written straight to FEATL
        float mean  = s1 * (1.0f / 365.0f);
        float var1  = (s2 - 365.0f * mean * mean) * (1.0f / 364.0f);
        float sigma = sqrtf(var1);
        float m3 = (s3 - 3.0f * mean * s2) * (1.0f / 365.0f) + 2.0f * mean * mean * mean;
        float mm = mean * mean;
        float m4 = (s4 - 4.0f * mean * s3 + 6.0f * mm * s2) * (1.0f / 365.0f) - 3.0f * mm * mm;
        float sg2 = sigma * sigma;
        float skew = m3 / (sigma * sg2 + 1e-8f);
        float kurt = m4 / (sg2 * sg2 + 1e-8f);
        float st[6] = { mean, sigma, mn, mx, skew, kurt };
        float f[8];
        #pragma unroll
        for (int c0 = 0; c0 < 8; ++c0) {
            int c = 8 * qq + c0;
            float acc = bsf[c];
            #pragma unroll
            for (int jj = 0; jj < 6; ++jj) acc += st[jj] * Wsf[jj * 32 + c];
            f[c0] = acc;
        }
        int4 w4;
        w4.x = (int)pk2(f[0], f[1]); w4.y = (int)pk2(f[2], f[3]);
        w4.z = (int)pk2(f[4], f[5]); w4.w = (int)pk2(f[6], f[7]);
        *(int4*)(FEATL + r0 * 40 + 8 * qq) = w4;
    }
    __syncthreads();                            // #1: XT ready

    // ---- G1: x @ W1, 2 straight-line passes, h1 parked packed in regs ----
    const short* Ap0 = XT + m * 376 + h * 8;
    const short* Ap1 = Ap0 + 32 * 376;
    unsigned park[2][2][2][8];                  // [pass][ct][rt][rr]
    #pragma unroll
    for (int p = 0; p < 2; ++p) {
        float16 c00, c01, c10, c11;             // c[ct][rt]
        #pragma unroll
        for (int i = 0; i < 16; ++i) { c00[i] = 0.f; c01[i] = 0.f; c10[i] = 0.f; c11[i] = 0.f; }
        const short* B1 = W1t + (256 * p + 64 * wv + m) * 16 + h * 8;
        #pragma unroll
        for (int kc = 0; kc < 23; ++kc) {
            short8 b0 = gld8(B1 + kc * 8192);
            short8 b1 = gld8(B1 + 512 + kc * 8192);
            short8 a0 = lds8(Ap0 + kc * 16);
            short8 a1 = lds8(Ap1 + kc * 16);
            c00 = mfma16(a0, b0, c00);
            c01 = mfma16(a1, b0, c01);
            c10 = mfma16(a0, b1, c10);
            c11 = mfma16(a1, b1, c11);
        }
        #pragma unroll
        for (int rr = 0; rr < 8; ++rr) {
            park[p][0][0][rr] = pk2(fmaxf(c00[2*rr] + bb1[p][0], 0.f), fmaxf(c00[2*rr+1] + bb1[p][0], 0.f));
            park[p][0][1][rr] = pk2(fmaxf(c01[2*rr] + bb1[p][0], 0.f), fmaxf(c01[2*rr+1] + bb1[p][0], 0.f));
            park[p][1][0][rr] = pk2(fmaxf(c10[2*rr] + bb1[p][1], 0.f), fmaxf(c10[2*rr+1] + bb1[p][1], 0.f));
            park[p][1][1][rr] = pk2(fmaxf(c11[2*rr] + bb1[p][1], 0.f), fmaxf(c11[2*rr+1] + bb1[p][1], 0.f));
        }
    }
    __syncthreads();                            // #2: G1 done, XT dead -> SB valid

    // ---- G2: h1 @ W2, K=512 as 4 slabs of 128, double-buffered, 1 barrier/slab ----
    float16 H00, H01, H10, H11;                 // H[ct][rt], h2 cols 64wv+32ct
    #pragma unroll
    for (int i = 0; i < 16; ++i) { H00[i] = 0.f; H01[i] = 0.f; H10[i] = 0.f; H11[i] = 0.f; }
    const short* A2r0 = SB0 + m * 136 + h * 8;  // recomputed per slab via SBs below
    #pragma unroll
    for (int s = 0; s < 4; ++s) {
        short* SBs = (s & 1) ? SB1 : SB0;
        if ((wv >> 1) == (s & 1)) {             // owner waves stage their park slab
            int p = s >> 1;
            int cb = 64 * (wv & 1) + m;
            #pragma unroll
            for (int ct = 0; ct < 2; ++ct)
            #pragma unroll
            for (int rt = 0; rt < 2; ++rt)
            #pragma unroll
            for (int rr = 0; rr < 8; ++rr) {
                unsigned pv = park[p][ct][rt][rr];
                int row = rt * 32 + rowof(2 * rr, h);
                SBs[row * 136 + cb + 32 * ct]       = (short)(pv & 0xffffu);
                SBs[(row + 1) * 136 + cb + 32 * ct] = (short)(pv >> 16);
            }
        }
        __syncthreads();                        // #3..#6
        const short* A0p = SBs + m * 136 + h * 8;
        const short* A1p = A0p + 32 * 136;
        const short* B2 = W2t + (64 * wv + m) * 16 + h * 8 + s * 32768;
        #pragma unroll
        for (int i = 0; i < 8; ++i) {
            short8 b0 = gld8(B2 + i * 4096);
            short8 b1 = gld8(B2 + 512 + i * 4096);
            short8 a0 = lds8(A0p + i * 16);
            short8 a1 = lds8(A1p + i * 16);
            H00 = mfma16(a0, b0, H00);
            H01 = mfma16(a1, b0, H01);
            H10 = mfma16(a0, b1, H10);
            H11 = mfma16(a1, b1, H11);
        }
    }
    (void)A2r0;

    // ---- G3: seq = relu(h2 @ W3 + b3), K=256 as 2 slabs, 1 barrier/slab ----
    float16 S0, S1;                             // seq cols 32wv, row-tiles 0/1
    #pragma unroll
    for (int i = 0; i < 16; ++i) { S0[i] = 0.f; S1[i] = 0.f; }
    #pragma unroll
    for (int t = 0; t < 2; ++t) {
        short* SBs = t ? SB1 : SB0;
        if ((wv >> 1) == t) {                   // owner waves stage h2 slab
            int cb = 64 * (wv & 1) + m;
            #pragma unroll
            for (int rr = 0; rr < 8; ++rr) {
                int rw0 = rowof(2 * rr, h);
                SBs[rw0 * 136 + cb]              = f2bf(fmaxf(H00[2*rr]   + bb2[0], 0.f));
                SBs[(rw0 + 1) * 136 + cb]        = f2bf(fmaxf(H00[2*rr+1] + bb2[0], 0.f));
                SBs[(32 + rw0) * 136 + cb]       = f2bf(fmaxf(H01[2*rr]   + bb2[0], 0.f));
                SBs[(33 + rw0) * 136 + cb]       = f2bf(fmaxf(H01[2*rr+1] + bb2[0], 0.f));
                SBs[rw0 * 136 + cb + 32]         = f2bf(fmaxf(H10[2*rr]   + bb2[1], 0.f));
                SBs[(rw0 + 1) * 136 + cb + 32]   = f2bf(fmaxf(H10[2*rr+1] + bb2[1], 0.f));
                SBs[(32 + rw0) * 136 + cb + 32]  = f2bf(fmaxf(H11[2*rr]   + bb2[1], 0.f));
                SBs[(33 + rw0) * 136 + cb + 32]  = f2bf(fmaxf(H11[2*rr+1] + bb2[1], 0.f));
            }
        }
        __syncthreads();                        // #7, #8
        const short* A0p = SBs + m * 136 + h * 8;
        const short* A1p = A0p + 32 * 136;
        const short* B3 = W3t + (32 * wv + m) * 16 + h * 8 + t * 16384;
        #pragma unroll
        for (int i = 0; i < 8; ++i) {
            short8 b  = gld8(B3 + i * 2048);
            short8 a0 = lds8(A0p + i * 16);
            short8 a1 = lds8(A1p + i * 16);
            S0 = mfma16(a0, b, S0);
            S1 = mfma16(a1, b, S1);
        }
    }

    // ---- stage seq -> SB0 (all waves, 32 cols each) ----
    {
        int cb = 32 * wv + m;
        #pragma unroll
        for (int rr = 0; rr < 8; ++rr) {
            int rw0 = rowof(2 * rr, h);
            SB0[rw0 * 136 + cb]        = f2bf(fmaxf(S0[2*rr]   + bb3, 0.f));
            SB0[(rw0 + 1) * 136 + cb]  = f2bf(fmaxf(S0[2*rr+1] + bb3, 0.f));
            SB0[(32 + rw0) * 136 + cb] = f2bf(fmaxf(S1[2*rr]   + bb3, 0.f));
            SB0[(33 + rw0) * 136 + cb] = f2bf(fmaxf(S1[2*rr+1] + bb3, 0.f));
        }
    }
    __syncthreads();                            // #9

    // ---- G4: c1 = relu([seq|feat] @ Wc1 + bc1), all 4 waves ----
    {
        int rt4 = wv >> 1, c4 = wv & 1;
        float16 g4;
        #pragma unroll
        for (int i = 0; i < 16; ++i) g4[i] = 0.f;
        const short* A4 = SB0 + (rt4 * 32 + m) * 136 + h * 8;
        const short* B4 = Wc1t + (32 * c4 + m) * 16 + h * 8;
        #pragma unroll
        for (int i = 0; i < 8; ++i)
            g4 = mfma16(lds8(A4 + i * 16), gld8(B4 + i * 1024), g4);
        const short* AF = FEATL + (rt4 * 32 + m) * 40 + h * 8;
        #pragma unroll
        for (int i = 0; i < 2; ++i)
            g4 = mfma16(lds8(AF + i * 16), gld8(B4 + (8 + i) * 1024), g4);
        short* C1 = SB1;                        // c1 [64][72] in SB1 region
        #pragma unroll
        for (int r = 0; r < 16; ++r)
            C1[(rt4 * 32 + rowof(r, h)) * 72 + 32 * c4 + m] = f2bf(fmaxf(g4[r] + bbc1, 0.f));
    }
    __syncthreads();                            // #10

    // ---- G5: c2 = relu(c1 @ Wc2 + bc2) -> C2 f32, waves 0..1 ----
    if (wv < 2) {
        const short* A5 = SB1 + (32 * wv + m) * 72 + h * 8;
        const short* B5 = Wc2t + m * 16 + h * 8;
        float16 g5;
        #pragma unroll
        for (int i = 0; i < 16; ++i) g5[i] = 0.f;
        #pragma unroll
        for (int i = 0; i < 4; ++i)
            g5 = mfma16(lds8(A5 + i * 16), gld8(B5 + i * 512), g5);
        #pragma unroll
        for (int r = 0; r < 16; ++r)
            C2f[(32 * wv + rowof(r, h)) * 33 + m] = fmaxf(g5[r] + bbc2, 0.f);
    }
    __syncthreads();                            // #11

    // ---- final: out = sigmoid(c2 . Wc3 + bc3) ----
    if (tid < 64) {
        float z = bc3f[0];
        #pragma unroll
        for (int i = 0; i < 32; ++i) z += C2f[tid * 33 + i] * Wc3f[i];
        out[rowBase + tid] = 1.0f / (1.0f + expf(-z));
    }
}

extern "C" void kernel_launch(void* const* d_in, const int* in_sizes, int n_in,
                              void* d_out, int out_size, void* d_ws, size_t ws_size,
                              hipStream_t stream)
{
    (void)in_sizes; (void)n_in; (void)out_size; (void)ws_size;
    const float* x   = (const float*)d_in[0];
    const float* W1  = (const float*)d_in[1];
    const float* b1  = (const float*)d_in[2];
    const float* W2  = (const float*)d_in[3];
    const float* b2  = (const float*)d_in[4];
    const float* W3  = (const float*)d_in[5];
    const float* b3  = (const float*)d_in[6];
    const float* Ws  = (const float*)d_in[7];
    const float* bs  = (const float*)d_in[8];
    const float* Wc1 = (const float*)d_in[9];
    const float* bc1 = (const float*)d_in[10];
    const float* Wc2 = (const float*)d_in[11];
    const float* bc2 = (const float*)d_in[12];
    const float* Wc3 = (const float*)d_in[13];
    const float* bc3 = (const float*)d_in[14];
    short* ws = (short*)d_ws;

    prep_v2<<<358, 256, 0, stream>>>(W1, W2, W3, Wc1, Wc2, ws);
    fused_v5<<<1024, 256, 0, stream>>>(x, b1, b2, b3, Ws, bs, bc1, bc2, Wc3, bc3,
                                       ws, (float*)d_out);
}